// Round 12
// baseline (119.047 us; speedup 1.0000x reference)
//
#include <hip/hip_runtime.h>

typedef unsigned int uint;
typedef unsigned short ushort;
typedef __attribute__((ext_vector_type(8))) short short8;
typedef __attribute__((ext_vector_type(4))) float f32x4;
typedef __attribute__((ext_vector_type(4))) float float4v;
typedef __attribute__((ext_vector_type(4))) ushort ushort4v;
typedef __attribute__((ext_vector_type(2))) uint uint2v;

constexpr int Edim = 768;
constexpr int Kdim = 768;   // C*P*P
constexpr int Mdim = 25088; // B*Npatch
constexpr int BM = 224, BN = 384, BK = 64;
constexpr int KSTEPS = Kdim / BK;        // 12
constexpr int MB_TILES = Mdim / BM;      // 112
constexpr int EB_TILES = Edim / BN;      // 2
constexpr int NWG = MB_TILES * EB_TILES; // 224 = 8*28 -> single round, exact swizzle

// ws layout
constexpr size_t WS_AMAXARR = 0;            // NWG floats
constexpr size_t WS_WSF = 8192;
constexpr size_t WS_BIAS = 12288;
constexpr size_t WS_WINT = 16384;           // int8 W [E][K] (590 KB, slot kept large)
constexpr size_t WS_APAT = 16384 + 1179648; // 25088*768*2 bf16 A
constexpr size_t WS_PQ = WS_APAT + (size_t)Mdim * Kdim * 2; // bf16 preout
constexpr size_t WS_NEED = WS_PQ + (size_t)Mdim * Edim * 2;

// round-to-nearest-even f32 -> bf16
__device__ __forceinline__ ushort f2bf(float f) {
  uint u = __float_as_uint(f);
  return (ushort)((u + 0x7fffu + ((u >> 16) & 1u)) >> 16);
}
__device__ __forceinline__ float bf2f(ushort b) {
  return __uint_as_float(((uint)b) << 16);
}

__device__ __forceinline__ void gload16(const ushort* g, ushort* l) {
  auto gp = (const __attribute__((address_space(1))) uint*)(const void*)g;
  auto lp = (__attribute__((address_space(3))) uint*)(void*)l;
  __builtin_amdgcn_global_load_lds(gp, lp, 16, 0, 0);
}
__device__ __forceinline__ void gload16c(const signed char* g, signed char* l) {
  auto gp = (const __attribute__((address_space(1))) uint*)(const void*)g;
  auto lp = (__attribute__((address_space(3))) uint*)(void*)l;
  __builtin_amdgcn_global_load_lds(gp, lp, 16, 0, 0);
}

// int8x8 (as uint2) -> bf16x8; values in [-127,127] are exact in bf16
__device__ __forceinline__ short8 i8tobf(uint2v w) {
  short8 r;
#pragma unroll
  for (int j = 0; j < 4; ++j) {
    r[j]     = (short)f2bf((float)(int)(signed char)(w.x >> (8 * j)));
    r[j + 4] = (short)f2bf((float)(int)(signed char)(w.y >> (8 * j)));
  }
  return r;
}

// ---------------- fused: weight quant (blocks 0..767) + patchify ------------
__global__ void prep_patch_kernel(const float* __restrict__ weight,
                                  const float* __restrict__ bias,
                                  const float* __restrict__ sfin,
                                  signed char* __restrict__ w_int8,
                                  float* __restrict__ w_sf,
                                  float* __restrict__ bias_out,
                                  const float* __restrict__ x,
                                  ushort* __restrict__ A, int n4) {
  const int t = threadIdx.x;
  if (blockIdx.x < Edim) {
    __shared__ float red[256];
    const int e = blockIdx.x;
    const float* wrow = weight + e * Kdim;
    float mx = 0.f;
    for (int k = t; k < Kdim; k += 256) mx = fmaxf(mx, fabsf(wrow[k]));
    red[t] = mx;
    __syncthreads();
    for (int s = 128; s > 0; s >>= 1) {
      if (t < s) red[t] = fmaxf(red[t], red[t + s]);
      __syncthreads();
    }
    const float sf = red[0] / 127.0f;
    for (int k = t; k < Kdim; k += 256)
      w_int8[e * Kdim + k] = (signed char)rintf(wrow[k] / sf);
    if (t == 0) {
      float conv = sf * sfin[0];
      w_sf[e] = sf;
      bias_out[e] = rintf(bias[e] / conv) * conv;
    }
  } else {
    const int nb = gridDim.x - Edim;
    const int stride = nb * 256;
    for (int i4 = (blockIdx.x - Edim) * 256 + t; i4 < n4; i4 += stride) {
      const int i = i4 * 4;
      const int w = i % 224;
      const int t1 = i / 224;
      const int h = t1 % 224;
      const int t2 = t1 / 224;
      const int c = t2 % 3;
      const int b = t2 / 3;
      float4v v = *(const float4v*)(x + i);
      ushort4v u;
      u.x = f2bf(v.x); u.y = f2bf(v.y); u.z = f2bf(v.z); u.w = f2bf(v.w);
      const int m = b * 196 + (h >> 4) * 14 + (w >> 4);
      const int d = c * 256 + (h & 15) * 16 + (w & 15);
      *(ushort4v*)(A + m * Kdim + d) = u;
    }
  }
}

// ---------------- GEMM: 224x384, int8 B, single round, counted vmcnt --------
// Delivery model: T_block = staged bytes / (~10 B/cyc/CU); minimize bytes/block
// AND keep NWG<=256 (no round quantization). B staged as int8 (exact), expanded
// to bf16 at frag-read. A: 3-stage XOR-swizzled bf16 (r9 staging). B: 2-stage
// LINEAR int8 (dest & src linear; bank conflicts negligible at port-bound).
// Issue order per K-step: B(kb+1) first, A(kb+2) after -> end-of-step
// s_waitcnt vmcnt(1) leaves only A(kb+2)'s newest load outstanding; valid for
// both wave groups (t<256 waves have one extra A load, which is the allowed 1).
template <bool BF16OUT>
__global__ __launch_bounds__(512, 2) void gemm9_kernel(
    const ushort* __restrict__ A, const signed char* __restrict__ Bw,
    const float* __restrict__ w_sf, const float* __restrict__ bias_out,
    float* __restrict__ out, ushort* __restrict__ pq,
    float* __restrict__ amax_arr) {
  __shared__ __align__(16) ushort As[3][BM * BK];      // 3 x 28 KB = 84 KB
  __shared__ __align__(16) signed char Bs[2][BN * BK]; // 2 x 24 KB = 48 KB
  __shared__ float sred[8];

  const int t = threadIdx.x;
  // XCD swizzle: NWG = 224 = 8*28 exact
  const int orig = blockIdx.x;
  const int wgid = (orig & 7) * (NWG / 8) + (orig >> 3);
  const int mb = wgid >> 1; // EB_TILES = 2
  const int eb = wgid & 1;
  const int m0 = mb * BM, e0 = eb * BN;

  // A staging (r9 pattern): chunk c = p*512 + t (p=0..2) and c = 1536 + t (t<256)
  // row = c>>3 (0..223), slot = c&7; logical col cb = slot^(row&7) = (t&7)^((t>>3)&7)
  const int cbs = (t & 7) ^ ((t >> 3) & 7);
  const ushort* ag = A + (size_t)(m0 + (t >> 3)) * Kdim + cbs * 8;
  // B staging LINEAR: chunk c = p*512 + t; row = c>>2 (0..383), col16 = c&3
  const signed char* bg = Bw + (size_t)(e0 + (t >> 2)) * Kdim + (t & 3) * 16;

  const int lane = t & 63;
  const int wv = t >> 6;             // 8 waves: 2M x 4N
  const int wrow0 = (wv >> 2) * 112; // 0/112
  const int wcol0 = (wv & 3) * 96;   // 0..288
  const int l15 = lane & 15, l4 = lane >> 4;
  int arow[7], brow[6];
#pragma unroll
  for (int i = 0; i < 7; ++i) arow[i] = wrow0 + i * 16 + l15;
#pragma unroll
  for (int i = 0; i < 6; ++i) brow[i] = wcol0 + i * 16 + l15;

  f32x4 acc[7][6] = {};

  auto stageA = [&](int kb, int st, int p) {
    gload16(ag + kb * 64 + p * 64 * Kdim, &As[st][(p * 512 + t) * 8]);
  };
  auto stageAx = [&](int kb, int st) { // extra 32 rows, waves 0-3 only
    if (t < 256) gload16(ag + kb * 64 + 192 * Kdim, &As[st][(1536 + t) * 8]);
  };
  auto stageB = [&](int kb, int st, int p) {
    gload16c(bg + kb * 64 + (size_t)p * 128 * Kdim, &Bs[st][(p * 512 + t) * 16]);
  };

  // prologue: A0 (3.5 passes), B0 (3), A1 (3.5); then wait A0+B0 landed:
  // queue newest->: A1 loads (3 or 4) -> vmcnt(3) correct for both wave groups
#pragma unroll
  for (int p = 0; p < 3; ++p) stageA(0, 0, p);
  stageAx(0, 0);
#pragma unroll
  for (int p = 0; p < 3; ++p) stageB(0, 0, p);
#pragma unroll
  for (int p = 0; p < 3; ++p) stageA(1, 1, p);
  stageAx(1, 1);
  asm volatile("s_waitcnt vmcnt(3)\n\ts_barrier" ::: "memory");
  __builtin_amdgcn_sched_barrier(0);

#pragma unroll
  for (int kb = 0; kb < KSTEPS; ++kb) {
    const int stA = kb % 3;
    const int stA2 = (kb + 2) % 3;
    const int stB = kb & 1;

    // ---------------- phase A (kk = 0) ----------------
    if (kb + 1 < KSTEPS) { // B(kb+1) p0,p1 FIRST
      stageB(kb + 1, stB ^ 1, 0);
      stageB(kb + 1, stB ^ 1, 1);
    }
    if (kb + 2 < KSTEPS) { // A(kb+2) p0,p1
      stageA(kb + 2, stA2, 0);
      stageA(kb + 2, stA2, 1);
    }
    short8 a0[7], b0[6];
    {
      const int cb = l4;
#pragma unroll
      for (int i = 0; i < 7; ++i)
        a0[i] = *(const short8*)&As[stA][arow[i] * 64 + ((cb ^ (arow[i] & 7)) << 3)];
#pragma unroll
      for (int i = 0; i < 6; ++i)
        b0[i] = i8tobf(*(const uint2v*)&Bs[stB][brow[i] * 64 + l4 * 8]);
    }
    asm volatile("s_waitcnt lgkmcnt(0)" ::: "memory");
    __builtin_amdgcn_sched_barrier(0);
    __builtin_amdgcn_s_setprio(1);
#pragma unroll
    for (int mi = 0; mi < 7; ++mi)
#pragma unroll
      for (int ni = 0; ni < 6; ++ni)
        acc[mi][ni] = __builtin_amdgcn_mfma_f32_16x16x32_bf16(
            a0[mi], b0[ni], acc[mi][ni], 0, 0, 0);
    __builtin_amdgcn_s_setprio(0);
    // pre-read kk=1 frags BEFORE the mid barrier (same validated buffers)
    short8 a1[7], b1[6];
    {
      const int cb = 4 + l4;
#pragma unroll
      for (int i = 0; i < 7; ++i)
        a1[i] = *(const short8*)&As[stA][arow[i] * 64 + ((cb ^ (arow[i] & 7)) << 3)];
#pragma unroll
      for (int i = 0; i < 6; ++i)
        b1[i] = i8tobf(*(const uint2v*)&Bs[stB][brow[i] * 64 + 32 + l4 * 8]);
    }
    __builtin_amdgcn_s_barrier(); // rhythm barrier (no drain)

    // ---------------- phase B (kk = 1) ----------------
    if (kb + 1 < KSTEPS) stageB(kb + 1, stB ^ 1, 2); // B FIRST
    if (kb + 2 < KSTEPS) {
      stageA(kb + 2, stA2, 2);
      stageAx(kb + 2, stA2);
    }
    asm volatile("s_waitcnt lgkmcnt(0)" ::: "memory");
    __builtin_amdgcn_sched_barrier(0);
    __builtin_amdgcn_s_setprio(1);
#pragma unroll
    for (int mi = 0; mi < 7; ++mi)
#pragma unroll
      for (int ni = 0; ni < 6; ++ni)
        acc[mi][ni] = __builtin_amdgcn_mfma_f32_16x16x32_bf16(
            a1[mi], b1[ni], acc[mi][ni], 0, 0, 0);
    __builtin_amdgcn_s_setprio(0);

    if (kb < KSTEPS - 1) {
      __builtin_amdgcn_sched_barrier(0);
      if (kb + 2 < KSTEPS) // only A(kb+2)'s newest load may stay outstanding
        asm volatile("s_waitcnt vmcnt(1)\n\ts_barrier" ::: "memory");
      else                 // kb = 10: drain B(11); nothing else in flight
        asm volatile("s_waitcnt vmcnt(0)\n\ts_barrier" ::: "memory");
      __builtin_amdgcn_sched_barrier(0);
    }
  }

  // epilogue: scale + bias, absmax, store bf16 preout (or f32 fallback)
  float amax = 0.f;
#pragma unroll
  for (int ni = 0; ni < 6; ++ni) {
    const int e = e0 + wcol0 + ni * 16 + l15;
    const float s = w_sf[e], bo = bias_out[e];
#pragma unroll
    for (int mi = 0; mi < 7; ++mi) {
      const int mr = m0 + wrow0 + mi * 16 + l4 * 4;
#pragma unroll
      for (int q = 0; q < 4; ++q) {
        float v = acc[mi][ni][q] * s + bo;
        amax = fmaxf(amax, fabsf(v));
        if (BF16OUT)
          pq[(size_t)(mr + q) * Edim + e] = f2bf(v);
        else
          out[(size_t)(mr + q) * Edim + e] = v;
      }
    }
  }
  // per-block reduce -> ONE plain store (no atomics)
#pragma unroll
  for (int off = 32; off > 0; off >>= 1)
    amax = fmaxf(amax, __shfl_xor(amax, off));
  if (lane == 0) sred[wv] = amax;
  __syncthreads();
  if (t == 0) {
    float m = sred[0];
#pragma unroll
    for (int i = 1; i < 8; ++i) m = fmaxf(m, sred[i]);
    amax_arr[blockIdx.x] = m;
  }
}

// ---------------- requantize from bf16 preout -> f32 out ----------------
__global__ void requant_bf16_kernel(const ushort* __restrict__ pq,
                                    float* __restrict__ out,
                                    const float* __restrict__ amax_arr,
                                    float* __restrict__ sf_out, int n8) {
  __shared__ float smax[4];
  const int t = threadIdx.x;
  float m = 0.f;
  for (int i = t; i < NWG; i += 256) m = fmaxf(m, amax_arr[i]);
#pragma unroll
  for (int off = 32; off > 0; off >>= 1) m = fmaxf(m, __shfl_xor(m, off));
  if ((t & 63) == 0) smax[t >> 6] = m;
  __syncthreads();
  m = fmaxf(fmaxf(smax[0], smax[1]), fmaxf(smax[2], smax[3]));

  const float act_sf = m / 127.0f;
  const float inv = 127.0f / m;
  const int idx = blockIdx.x * blockDim.x + t;
  if (idx == 0) *sf_out = act_sf;
  const short8* p8 = (const short8*)pq;
  const int stride = gridDim.x * blockDim.x;
  for (int i = idx; i < n8; i += stride) {
    short8 p = p8[i];
    float4v o0, o1;
    o0.x = rintf(bf2f((ushort)p[0]) * inv) * act_sf;
    o0.y = rintf(bf2f((ushort)p[1]) * inv) * act_sf;
    o0.z = rintf(bf2f((ushort)p[2]) * inv) * act_sf;
    o0.w = rintf(bf2f((ushort)p[3]) * inv) * act_sf;
    o1.x = rintf(bf2f((ushort)p[4]) * inv) * act_sf;
    o1.y = rintf(bf2f((ushort)p[5]) * inv) * act_sf;
    o1.z = rintf(bf2f((ushort)p[6]) * inv) * act_sf;
    o1.w = rintf(bf2f((ushort)p[7]) * inv) * act_sf;
    ((float4v*)out)[i * 2] = o0;
    ((float4v*)out)[i * 2 + 1] = o1;
  }
}

// ---------------- fallback: requantize f32 in place ----------------
__global__ void requant_f32_kernel(float* __restrict__ out,
                                   const float* __restrict__ amax_arr,
                                   float* __restrict__ sf_out, int n4) {
  __shared__ float smax[4];
  const int t = threadIdx.x;
  float m = 0.f;
  for (int i = t; i < NWG; i += 256) m = fmaxf(m, amax_arr[i]);
#pragma unroll
  for (int off = 32; off > 0; off >>= 1) m = fmaxf(m, __shfl_xor(m, off));
  if ((t & 63) == 0) smax[t >> 6] = m;
  __syncthreads();
  m = fmaxf(fmaxf(smax[0], smax[1]), fmaxf(smax[2], smax[3]));

  const float act_sf = m / 127.0f;
  const float inv = 127.0f / m;
  const int idx = blockIdx.x * blockDim.x + t;
  if (idx == 0) *sf_out = act_sf;
  float4v* o = (float4v*)out;
  const int stride = gridDim.x * blockDim.x;
  for (int i = idx; i < n4; i += stride) {
    float4v v = o[i];
    v.x = rintf(v.x * inv) * act_sf;
    v.y = rintf(v.y * inv) * act_sf;
    v.z = rintf(v.z * inv) * act_sf;
    v.w = rintf(v.w * inv) * act_sf;
    o[i] = v;
  }
}

extern "C" void kernel_launch(void* const* d_in, const int* in_sizes, int n_in,
                              void* d_out, int out_size, void* d_ws, size_t ws_size,
                              hipStream_t stream) {
  const float* x = (const float*)d_in[0];
  const float* weight = (const float*)d_in[1];
  const float* bias = (const float*)d_in[2];
  const float* sfin = (const float*)d_in[3];
  float* out = (float*)d_out;

  char* ws = (char*)d_ws;
  float* amax_arr = (float*)(ws + WS_AMAXARR);
  float* w_sf = (float*)(ws + WS_WSF);
  float* bias_out = (float*)(ws + WS_BIAS);
  signed char* w_int8 = (signed char*)(ws + WS_WINT);
  ushort* A = (ushort*)(ws + WS_APAT);
  ushort* pq = (ushort*)(ws + WS_PQ);

  const int n4 = (128 * 3 * 224 * 224) / 4;
  prep_patch_kernel<<<Edim + 2048, 256, 0, stream>>>(
      weight, bias, sfin, w_int8, w_sf, bias_out, x, A, n4);

  const int nout = out_size - 1; // 25088*768
  if (ws_size >= WS_NEED) {
    gemm9_kernel<true><<<NWG, 512, 0, stream>>>(A, w_int8, w_sf, bias_out,
                                                nullptr, pq, amax_arr);
    requant_bf16_kernel<<<2048, 256, 0, stream>>>(pq, out, amax_arr,
                                                  out + nout, nout / 8);
  } else {
    gemm9_kernel<false><<<NWG, 512, 0, stream>>>(A, w_int8, w_sf, bias_out,
                                                 out, nullptr, amax_arr);
    requant_f32_kernel<<<2048, 256, 0, stream>>>(out, amax_arr, out + nout,
                                                 nout / 4);
  }
}

// Round 13
// 97.174 us; speedup vs baseline: 1.2251x; 1.2251x over previous
//
#include <hip/hip_runtime.h>
#include <hip/hip_fp16.h>

typedef unsigned int uint;
typedef unsigned short ushort;
typedef __attribute__((ext_vector_type(8))) short short8;
typedef __attribute__((ext_vector_type(16))) float f32x16;
typedef __attribute__((ext_vector_type(4))) float float4v;
typedef __attribute__((ext_vector_type(4))) ushort ushort4v;
typedef __attribute__((ext_vector_type(2))) uint uint2v;
typedef __attribute__((ext_vector_type(4))) uint uint4v;

constexpr int Edim = 768;
constexpr int Kdim = 768;   // C*P*P
constexpr int Mdim = 25088; // B*Npatch
constexpr int BM = 256, BN = 128, BK = 64;
constexpr int KSTEPS = Kdim / BK;        // 12
constexpr int MB_TILES = Mdim / BM;      // 98
constexpr int EB_TILES = Edim / BN;      // 6
constexpr int NWG = MB_TILES * EB_TILES; // 588

// ws layout
constexpr size_t WS_AMAXARR = 0;            // NWG floats
constexpr size_t WS_WSF = 8192;
constexpr size_t WS_BIAS = 12288;
constexpr size_t WS_WINT = 16384;           // int8 W [E][K] (590 KB in 1.2MB slot)
constexpr size_t WS_APAT = 16384 + 1179648; // 25088*768*2 f16 A
constexpr size_t WS_PQ = WS_APAT + (size_t)Mdim * Kdim * 2; // bf16 preout
constexpr size_t WS_NEED = WS_PQ + (size_t)Mdim * Edim * 2;

// round-to-nearest-even f32 -> bf16
__device__ __forceinline__ ushort f2bf(float f) {
  uint u = __float_as_uint(f);
  return (ushort)((u + 0x7fffu + ((u >> 16) & 1u)) >> 16);
}
__device__ __forceinline__ float bf2f(ushort b) {
  return __uint_as_float(((uint)b) << 16);
}
__device__ __forceinline__ ushort f2h(float f) {
  __half h = __float2half(f);
  return *(ushort*)&h;
}

__device__ __forceinline__ void gload16(const void* g, void* l) {
  auto gp = (const __attribute__((address_space(1))) uint*)g;
  auto lp = (__attribute__((address_space(3))) uint*)l;
  __builtin_amdgcn_global_load_lds(gp, lp, 16, 0, 0);
}

// 8 int8 (uint2) -> 8 f16 (short8). v ∈ [-127,127] exact in f16.
// byte b = v+128 (after ^0x80); f16(0x6400|b) = 1024+b; subtract 1152 -> v.
__device__ __forceinline__ short8 i8x8_to_h8(uint2v w) {
  const uint c64 = 0x64646464u;
  const uint lo = w.x ^ 0x80808080u, hi = w.y ^ 0x80808080u;
  uint d0 = __builtin_amdgcn_perm(c64, lo, 0x04010400u); // [64 b1 64 b0]
  uint d1 = __builtin_amdgcn_perm(c64, lo, 0x04030402u); // [64 b3 64 b2]
  uint d2 = __builtin_amdgcn_perm(c64, hi, 0x04010400u);
  uint d3 = __builtin_amdgcn_perm(c64, hi, 0x04030402u);
  const __half2 off = __float2half2_rn(-1152.0f);
  __half2 h0 = __hadd2(*(__half2*)&d0, off); // v_pk_add_f16
  __half2 h1 = __hadd2(*(__half2*)&d1, off);
  __half2 h2 = __hadd2(*(__half2*)&d2, off);
  __half2 h3 = __hadd2(*(__half2*)&d3, off);
  uint4v q = {*(uint*)&h0, *(uint*)&h1, *(uint*)&h2, *(uint*)&h3};
  return *(short8*)&q;
}

// ---------------- fused: weight quant (blocks 0..767) + patchify ------------
__global__ void prep_patch_kernel(const float* __restrict__ weight,
                                  const float* __restrict__ bias,
                                  const float* __restrict__ sfin,
                                  signed char* __restrict__ w_int8,
                                  float* __restrict__ w_sf,
                                  float* __restrict__ bias_out,
                                  const float* __restrict__ x,
                                  ushort* __restrict__ A, int n4) {
  const int t = threadIdx.x;
  if (blockIdx.x < Edim) {
    __shared__ float red[256];
    const int e = blockIdx.x;
    const float* wrow = weight + e * Kdim;
    float mx = 0.f;
    for (int k = t; k < Kdim; k += 256) mx = fmaxf(mx, fabsf(wrow[k]));
    red[t] = mx;
    __syncthreads();
    for (int s = 128; s > 0; s >>= 1) {
      if (t < s) red[t] = fmaxf(red[t], red[t + s]);
      __syncthreads();
    }
    const float sf = red[0] / 127.0f;
    for (int k = t; k < Kdim; k += 256)
      w_int8[e * Kdim + k] = (signed char)rintf(wrow[k] / sf);
    if (t == 0) {
      float conv = sf * sfin[0];
      w_sf[e] = sf;
      bias_out[e] = rintf(bias[e] / conv) * conv;
    }
  } else {
    const int nb = gridDim.x - Edim;
    const int stride = nb * 256;
    for (int i4 = (blockIdx.x - Edim) * 256 + t; i4 < n4; i4 += stride) {
      const int i = i4 * 4;
      const int w = i % 224;
      const int t1 = i / 224;
      const int h = t1 % 224;
      const int t2 = t1 / 224;
      const int c = t2 % 3;
      const int b = t2 / 3;
      float4v v = *(const float4v*)(x + i);
      ushort4v u;
      u.x = f2h(v.x); u.y = f2h(v.y); u.z = f2h(v.z); u.w = f2h(v.w);
      const int m = b * 196 + (h >> 4) * 14 + (w >> 4);
      const int d = c * 256 + (h & 15) * 16 + (w & 15);
      *(ushort4v*)(A + m * Kdim + d) = u;
    }
  }
}

// ---------------- GEMM: 256x128, f16 A + int8 B, 32x32x16_f16, counted ------
// r10's verified structure/rhythm; only B is int8 (staged bytes/step 48->40KB).
// A LDS: [row 256][64 f16], chunk (row,cb8) at row*8 + (cb8^(row&7)) (16B gran).
// B LDS: [row 128][64 i8], 16B chunk (row,c16) at row*4 + (c16^((row>>1)&3)).
// Per K-step: 5 loads {B(kb+2) x1, A(kb+2) x4}; end-of-step wait vmcnt(5)
// guarantees tile kb+1 (issued previous step) fully landed. Never 0 till kb=10.
template <bool BF16OUT>
__global__ __launch_bounds__(512, 2) void gemm10_kernel(
    const ushort* __restrict__ A, const signed char* __restrict__ Bw,
    const float* __restrict__ w_sf, const float* __restrict__ bias_out,
    float* __restrict__ out, ushort* __restrict__ pq,
    float* __restrict__ amax_arr) {
  __shared__ __align__(16) ushort As[3][BM * BK];      // 3 x 32 KB
  __shared__ __align__(16) signed char Bs[3][BN * BK]; // 3 x 8 KB  (120 KB tot)
  __shared__ float sred[8];

  const int t = threadIdx.x;
  // bijective XCD swizzle for NWG=588 (m204 variant)
  const int qq = NWG >> 3, r8 = NWG & 7;
  const int xcd = blockIdx.x & 7, bidx = blockIdx.x >> 3;
  const int wgid = (xcd < r8 ? xcd * (qq + 1) : r8 * (qq + 1) + (xcd - r8) * qq) + bidx;
  const int mb = wgid / EB_TILES;
  const int eb = wgid - mb * EB_TILES;
  const int m0 = mb * BM, e0 = eb * BN;

  // A staging: chunk c = rr*512 + t; row = rr*64 + (t>>3); slot = t&7;
  // logical cb8 = (t&7)^((t>>3)&7)  (src pre-swizzled, dest linear)
  const int cbs = (t & 7) ^ ((t >> 3) & 7);
  const ushort* ag = A + (size_t)(m0 + (t >> 3)) * Kdim + cbs * 8;
  // B staging (1 pass, 512x16B = 8KB): row = t>>2, stored c16 = t&3,
  // logical c16 = (t&3)^((row>>1)&3) = (t&3)^((t>>3)&3)
  const signed char* bg = Bw + (size_t)(e0 + (t >> 2)) * Kdim +
                          (size_t)((t & 3) ^ ((t >> 3) & 3)) * 16;

  const int lane = t & 63;
  const int wv = t >> 6;            // 8 waves: 4M x 2N
  const int wrow0 = (wv >> 1) * 64; // 0..192
  const int wcol0 = (wv & 1) * 64;  // 0/64
  const int l31 = lane & 31, hi = lane >> 5;
  int arow[2], brow[2];
#pragma unroll
  for (int i = 0; i < 2; ++i) {
    arow[i] = wrow0 + i * 32 + l31;
    brow[i] = wcol0 + i * 32 + l31;
  }
  // B read byte offset for (row, cb8): row*64 + ((cb8>>1)^((row>>1)&3))*16 + (cb8&1)*8
  auto boff = [&](int row, int cb) {
    return row * 64 + ((((cb >> 1) ^ ((row >> 1) & 3))) << 4) + ((cb & 1) << 3);
  };

  f32x16 acc[2][2] = {};

  // prologue: tiles 0,1 (5 loads each: 4A + 1B)
#pragma unroll
  for (int pt = 0; pt < 2; ++pt) {
    const ushort* agk = ag + pt * 64;
#pragma unroll
    for (int rr = 0; rr < 4; ++rr)
      gload16(agk + rr * 64 * Kdim, &As[pt][(rr * 512 + t) * 8]);
    gload16(bg + pt * 64, &Bs[pt][t * 16]);
  }
  asm volatile("s_waitcnt vmcnt(5)\n\ts_barrier" ::: "memory"); // tile 0 landed
  __builtin_amdgcn_sched_barrier(0);

#pragma unroll
  for (int kb = 0; kb < KSTEPS; ++kb) {
    const int st = kb % 3;
    const int st2 = (kb + 2) % 3;

    // ---------------- phase A (kc = 0,1) ----------------
    if (kb + 2 < KSTEPS) { // stage: B(kb+2), A(kb+2) p0,p1
      gload16(bg + (kb + 2) * 64, &Bs[st2][t * 16]);
      const ushort* agk = ag + (kb + 2) * 64;
      gload16(agk + 0 * 64 * Kdim, &As[st2][(0 * 512 + t) * 8]);
      gload16(agk + 1 * 64 * Kdim, &As[st2][(1 * 512 + t) * 8]);
    }
    short8 a0[2][2], b0[2][2]; // [kc][frag]
#pragma unroll
    for (int kc = 0; kc < 2; ++kc) {
      const int cb = kc * 2 + hi;
#pragma unroll
      for (int i = 0; i < 2; ++i) {
        a0[kc][i] = *(const short8*)&As[st][arow[i] * 64 + ((cb ^ (arow[i] & 7)) << 3)];
        b0[kc][i] = i8x8_to_h8(*(const uint2v*)&Bs[st][boff(brow[i], cb)]);
      }
    }
    asm volatile("s_waitcnt lgkmcnt(0)" ::: "memory");
    __builtin_amdgcn_sched_barrier(0);
    __builtin_amdgcn_s_setprio(1);
#pragma unroll
    for (int kc = 0; kc < 2; ++kc)
#pragma unroll
      for (int mi = 0; mi < 2; ++mi)
#pragma unroll
        for (int ni = 0; ni < 2; ++ni)
          acc[mi][ni] = __builtin_amdgcn_mfma_f32_32x32x16_f16(
              a0[kc][mi], b0[kc][ni], acc[mi][ni], 0, 0, 0);
    __builtin_amdgcn_s_setprio(0);
    // read phase-B frags BEFORE the mid barrier (same validated buffer)
    short8 a1[2][2], b1[2][2];
#pragma unroll
    for (int kc = 0; kc < 2; ++kc) {
      const int cb = (kc + 2) * 2 + hi;
#pragma unroll
      for (int i = 0; i < 2; ++i) {
        a1[kc][i] = *(const short8*)&As[st][arow[i] * 64 + ((cb ^ (arow[i] & 7)) << 3)];
        b1[kc][i] = i8x8_to_h8(*(const uint2v*)&Bs[st][boff(brow[i], cb)]);
      }
    }
    __builtin_amdgcn_s_barrier(); // rhythm barrier (no drain)

    // ---------------- phase B (kc = 2,3) ----------------
    if (kb + 2 < KSTEPS) { // stage: A(kb+2) p2,p3
      const ushort* agk = ag + (kb + 2) * 64;
      gload16(agk + 2 * 64 * Kdim, &As[st2][(2 * 512 + t) * 8]);
      gload16(agk + 3 * 64 * Kdim, &As[st2][(3 * 512 + t) * 8]);
    }
    asm volatile("s_waitcnt lgkmcnt(0)" ::: "memory");
    __builtin_amdgcn_sched_barrier(0);
    __builtin_amdgcn_s_setprio(1);
#pragma unroll
    for (int kc = 0; kc < 2; ++kc)
#pragma unroll
      for (int mi = 0; mi < 2; ++mi)
#pragma unroll
        for (int ni = 0; ni < 2; ++ni)
          acc[mi][ni] = __builtin_amdgcn_mfma_f32_32x32x16_f16(
              a1[kc][mi], b1[kc][ni], acc[mi][ni], 0, 0, 0);
    __builtin_amdgcn_s_setprio(0);

    if (kb < KSTEPS - 1) {
      __builtin_amdgcn_sched_barrier(0);
      if (kb + 2 < KSTEPS) // allow this step's 5 newest; tile kb+1 landed
        asm volatile("s_waitcnt vmcnt(5)\n\ts_barrier" ::: "memory");
      else                 // kb = 10: drain tile 11
        asm volatile("s_waitcnt vmcnt(0)\n\ts_barrier" ::: "memory");
      __builtin_amdgcn_sched_barrier(0);
    }
  }

  // epilogue: scale + bias, absmax, store bf16 preout (or f32)
  // 32x32 C layout: col = lane&31, row = (r&3) + 8*(r>>2) + 4*hi
  float amax = 0.f;
#pragma unroll
  for (int ni = 0; ni < 2; ++ni) {
    const int e = e0 + wcol0 + ni * 32 + l31;
    const float s = w_sf[e], bo = bias_out[e];
#pragma unroll
    for (int mi = 0; mi < 2; ++mi) {
      const int mbase = m0 + wrow0 + mi * 32 + hi * 4;
#pragma unroll
      for (int r = 0; r < 16; ++r) {
        const int m = mbase + (r & 3) + ((r >> 2) << 3);
        float v = acc[mi][ni][r] * s + bo;
        amax = fmaxf(amax, fabsf(v));
        if (BF16OUT)
          pq[(size_t)m * Edim + e] = f2bf(v);
        else
          out[(size_t)m * Edim + e] = v;
      }
    }
  }
  // per-block reduce -> ONE plain store (no atomics)
#pragma unroll
  for (int off = 32; off > 0; off >>= 1)
    amax = fmaxf(amax, __shfl_xor(amax, off));
  if (lane == 0) sred[wv] = amax;
  __syncthreads();
  if (t == 0) {
    float m = sred[0];
#pragma unroll
    for (int i = 1; i < 8; ++i) m = fmaxf(m, sred[i]);
    amax_arr[blockIdx.x] = m;
  }
}

// ---------------- requantize from bf16 preout -> f32 out ----------------
__global__ void requant_bf16_kernel(const ushort* __restrict__ pq,
                                    float* __restrict__ out,
                                    const float* __restrict__ amax_arr,
                                    float* __restrict__ sf_out, int n8) {
  __shared__ float smax[4];
  const int t = threadIdx.x;
  float m = 0.f;
  for (int i = t; i < NWG; i += 256) m = fmaxf(m, amax_arr[i]);
#pragma unroll
  for (int off = 32; off > 0; off >>= 1) m = fmaxf(m, __shfl_xor(m, off));
  if ((t & 63) == 0) smax[t >> 6] = m;
  __syncthreads();
  m = fmaxf(fmaxf(smax[0], smax[1]), fmaxf(smax[2], smax[3]));

  const float act_sf = m / 127.0f;
  const float inv = 127.0f / m;
  const int idx = blockIdx.x * blockDim.x + t;
  if (idx == 0) *sf_out = act_sf;
  const short8* p8 = (const short8*)pq;
  const int stride = gridDim.x * blockDim.x;
  for (int i = idx; i < n8; i += stride) {
    short8 p = p8[i];
    float4v o0, o1;
    o0.x = rintf(bf2f((ushort)p[0]) * inv) * act_sf;
    o0.y = rintf(bf2f((ushort)p[1]) * inv) * act_sf;
    o0.z = rintf(bf2f((ushort)p[2]) * inv) * act_sf;
    o0.w = rintf(bf2f((ushort)p[3]) * inv) * act_sf;
    o1.x = rintf(bf2f((ushort)p[4]) * inv) * act_sf;
    o1.y = rintf(bf2f((ushort)p[5]) * inv) * act_sf;
    o1.z = rintf(bf2f((ushort)p[6]) * inv) * act_sf;
    o1.w = rintf(bf2f((ushort)p[7]) * inv) * act_sf;
    ((float4v*)out)[i * 2] = o0;
    ((float4v*)out)[i * 2 + 1] = o1;
  }
}

// ---------------- fallback: requantize f32 in place ----------------
__global__ void requant_f32_kernel(float* __restrict__ out,
                                   const float* __restrict__ amax_arr,
                                   float* __restrict__ sf_out, int n4) {
  __shared__ float smax[4];
  const int t = threadIdx.x;
  float m = 0.f;
  for (int i = t; i < NWG; i += 256) m = fmaxf(m, amax_arr[i]);
#pragma unroll
  for (int off = 32; off > 0; off >>= 1) m = fmaxf(m, __shfl_xor(m, off));
  if ((t & 63) == 0) smax[t >> 6] = m;
  __syncthreads();
  m = fmaxf(fmaxf(smax[0], smax[1]), fmaxf(smax[2], smax[3]));

  const float act_sf = m / 127.0f;
  const float inv = 127.0f / m;
  const int idx = blockIdx.x * blockDim.x + t;
  if (idx == 0) *sf_out = act_sf;
  float4v* o = (float4v*)out;
  const int stride = gridDim.x * blockDim.x;
  for (int i = idx; i < n4; i += stride) {
    float4v v = o[i];
    v.x = rintf(v.x * inv) * act_sf;
    v.y = rintf(v.y * inv) * act_sf;
    v.z = rintf(v.z * inv) * act_sf;
    v.w = rintf(v.w * inv) * act_sf;
    o[i] = v;
  }
}

extern "C" void kernel_launch(void* const* d_in, const int* in_sizes, int n_in,
                              void* d_out, int out_size, void* d_ws, size_t ws_size,
                              hipStream_t stream) {
  const float* x = (const float*)d_in[0];
  const float* weight = (const float*)d_in[1];
  const float* bias = (const float*)d_in[2];
  const float* sfin = (const float*)d_in[3];
  float* out = (float*)d_out;

  char* ws = (char*)d_ws;
  float* amax_arr = (float*)(ws + WS_AMAXARR);
  float* w_sf = (float*)(ws + WS_WSF);
  float* bias_out = (float*)(ws + WS_BIAS);
  signed char* w_int8 = (signed char*)(ws + WS_WINT);
  ushort* A = (ushort*)(ws + WS_APAT);
  ushort* pq = (ushort*)(ws + WS_PQ);

  const int n4 = (128 * 3 * 224 * 224) / 4;
  prep_patch_kernel<<<Edim + 2048, 256, 0, stream>>>(
      weight, bias, sfin, w_int8, w_sf, bias_out, x, A, n4);

  const int nout = out_size - 1; // 25088*768
  if (ws_size >= WS_NEED) {
    gemm10_kernel<true><<<NWG, 512, 0, stream>>>(A, w_int8, w_sf, bias_out,
                                                 nullptr, pq, amax_arr);
    requant_bf16_kernel<<<2048, 256, 0, stream>>>(pq, out, amax_arr,
                                                  out + nout, nout / 8);
  } else {
    gemm10_kernel<false><<<NWG, 512, 0, stream>>>(A, w_int8, w_sf, bias_out,
                                                  out, nullptr, amax_arr);
    requant_f32_kernel<<<2048, 256, 0, stream>>>(out, amax_arr, out + nout,
                                                 nout / 4);
  }
}